// Round 1
// baseline (957.411 us; speedup 1.0000x reference)
//
#include <hip/hip_runtime.h>
#include <stdint.h>
#include <stddef.h>

typedef _Float16 f16;
typedef _Float16 f16x8 __attribute__((ext_vector_type(8)));
typedef _Float16 f16x4 __attribute__((ext_vector_type(4)));
typedef float    f32x4 __attribute__((ext_vector_type(4)));

#define AS1 __attribute__((address_space(1)))
#define AS3 __attribute__((address_space(3)))

__device__ __forceinline__ void gl_lds16(const f16* g, f16* l) {
  // async global->LDS, 16B per lane; LDS dest must be uniform base + lane*16
  __builtin_amdgcn_global_load_lds((const AS1 uint32_t*)g, (AS3 uint32_t*)l, 16, 0, 0);
}

// Problem constants: B=32, H=W=56, C=512, nh=8, hd=64, ws=7, S=49, G=64
// tokens/batch = 3136, M_total = 100352

// ---------------------------------------------------------------------------
// k_prep: fp32->fp16 conversions + RoPE table (49 x 32 float2 cos/sin)
// ---------------------------------------------------------------------------
__global__ __launch_bounds__(256) void k_prep(
    const float* __restrict__ x, const float* __restrict__ wqkv,
    const float* __restrict__ wproj,
    f16* __restrict__ x16, f16* __restrict__ wqkv16, f16* __restrict__ wproj16,
    float2* __restrict__ tab)
{
  const int XB = 25088, WQ = 384, WP = 128;  // blocks per region (8 elems/thread)
  int b = blockIdx.x, t = threadIdx.x;
  const float* src; f16* dst; long i0;
  if (b < XB)            { src = x;     dst = x16;     i0 = ((long)b*256 + t)*8; }
  else if (b < XB+WQ)    { src = wqkv;  dst = wqkv16;  i0 = ((long)(b-XB)*256 + t)*8; }
  else if (b < XB+WQ+WP) { src = wproj; dst = wproj16; i0 = ((long)(b-XB-WQ)*256 + t)*8; }
  else {
    int id = (b - XB - WQ - WP)*256 + t;
    if (id < 49*32) {
      int s = id >> 5, i = id & 31, j = i >> 1;
      float freq = expf(-(float)(4*j)*(1.0f/64.0f)*9.210340372f); // 10000^(-4j/64)
      float pos = (i & 1) ? (float)(s/7) : (float)(s%7);          // odd=y, even=x
      float a = pos * freq;
      tab[id] = make_float2(cosf(a), sinf(a));
    }
    return;
  }
  const float4* s4 = (const float4*)(src + i0);
  float4 v0 = s4[0], v1 = s4[1];
  f16x8 h = { (f16)v0.x,(f16)v0.y,(f16)v0.z,(f16)v0.w,
              (f16)v1.x,(f16)v1.y,(f16)v1.z,(f16)v1.w };
  *(f16x8*)(dst + i0) = h;
}

// ---------------------------------------------------------------------------
// k_qkv: GEMM-BT  C[ch][tok] = sum_k W[ch][k] * X[tok][k]
//   block tile: 128 channels (grid.x, 12) x 128 tokens (grid.y, 784), BK=32
//   epilogue: RoPE on q/k, scatter to q/k [bgh][s][64] and vT [bgh][d][56]
// ---------------------------------------------------------------------------
__global__ __launch_bounds__(256) void k_qkv(
    const f16* __restrict__ x16, const f16* __restrict__ w16,
    const float2* __restrict__ tab,
    f16* __restrict__ qb, f16* __restrict__ kb, f16* __restrict__ vb)
{
  __shared__ __align__(16) f16 Wt[128*32];
  __shared__ __align__(16) f16 Xt[128*32];
  const int by = blockIdx.x;   // channel tile 0..11  (0-3 q, 4-7 k, 8-11 v)
  const int bx = blockIdx.y;   // token tile 0..783
  const int tid = threadIdx.x;
  const int wave = tid >> 6, ln = tid & 63;
  const int l15 = ln & 15, quad = ln >> 4;
  const int wq = wave >> 1, wp = wave & 1;   // wave quadrant: channel/token halves

  f32x4 acc[4][4] = {};

  const int srow = wave*32 + (ln >> 2);
  const int scol = (ln & 3)*8;
  const f16* gW = w16 + (size_t)(by*128 + srow)*512 + scol;
  const f16* gX = x16 + (size_t)(bx*128 + srow)*512 + scol;
  f16* lW = &Wt[srow*32 + scol];
  f16* lX = &Xt[srow*32 + scol];

  for (int kt = 0; kt < 16; ++kt) {
    __syncthreads();
    gl_lds16(gW,          lW);
    gl_lds16(gW + 16*512, lW + 16*32);
    gl_lds16(gX,          lX);
    gl_lds16(gX + 16*512, lX + 16*32);
    gW += 32; gX += 32;
    __syncthreads();
    f16x8 af[4], bf[4];
#pragma unroll
    for (int i = 0; i < 4; ++i) af[i] = *(const f16x8*)&Wt[(wq*64 + i*16 + l15)*32 + quad*8];
#pragma unroll
    for (int j = 0; j < 4; ++j) bf[j] = *(const f16x8*)&Xt[(wp*64 + j*16 + l15)*32 + quad*8];
#pragma unroll
    for (int i = 0; i < 4; ++i)
#pragma unroll
      for (int j = 0; j < 4; ++j)
        acc[i][j] = __builtin_amdgcn_mfma_f32_16x16x32_f16(af[i], bf[j], acc[i][j], 0, 0, 0);
  }

  const int t = (by*128) >> 9;   // 0=q,1=k,2=v (uniform per block)
#pragma unroll
  for (int j = 0; j < 4; ++j) {
    int m  = bx*128 + wp*64 + j*16 + l15;   // token (token-order)
    int b  = m / 3136;
    int nn = m - b*3136;
    int hh = nn / 56, ww = nn - hh*56;
    int gh = hh / 7,  p  = hh - gh*7;
    int gw = ww / 7,  qx = ww - gw*7;
    int g  = gh*8 + gw;
    int s  = p*7 + qx;
    int bg = b*64 + g;
#pragma unroll
    for (int i = 0; i < 4; ++i) {
      int c0   = by*128 + wq*64 + i*16 + quad*4;  // global channel of reg 0
      int cin  = c0 & 511;
      int head = cin >> 6;
      int dd   = cin & 63;                        // multiple of 4
      float v0 = acc[i][j][0], v1 = acc[i][j][1], v2 = acc[i][j][2], v3 = acc[i][j][3];
      if (t < 2) {
        float2 t0 = tab[s*32 + (dd >> 1)];
        float2 t1 = tab[s*32 + (dd >> 1) + 1];
        float r0 = v0*t0.x - v1*t0.y;
        float r1 = v0*t0.y + v1*t0.x;
        float r2 = v2*t1.x - v3*t1.y;
        float r3 = v2*t1.y + v3*t1.x;
        f16x4 h4 = { (f16)r0, (f16)r1, (f16)r2, (f16)r3 };
        f16* dst = (t == 0 ? qb : kb) + (size_t)((bg*8 + head)*49 + s)*64 + dd;
        *(f16x4*)dst = h4;
      } else {
        size_t base = (size_t)((bg*8 + head)*64 + dd)*56 + s;   // v transposed [d][56]
        vb[base      ] = (f16)v0;
        vb[base +  56] = (f16)v1;
        vb[base + 112] = (f16)v2;
        vb[base + 168] = (f16)v3;
      }
    }
  }
}

// ---------------------------------------------------------------------------
// k_attn: one wave per (b,g,head).  S=49 padded to 64 via clamp+mask.
// ---------------------------------------------------------------------------
__global__ __launch_bounds__(64) void k_attn(
    const f16* __restrict__ qb, const f16* __restrict__ kb,
    const f16* __restrict__ vb, f16* __restrict__ ob)
{
  __shared__ __align__(16) f16 P[64*72];   // unnormalized exp, stride 72 (144B)
  __shared__ float lsum[64];
  const int bid = blockIdx.x;
  const int ln = threadIdx.x, l15 = ln & 15, quad = ln >> 4;
  const f16* q = qb + (size_t)bid*(49*64);
  const f16* k = kb + (size_t)bid*(49*64);
  const f16* v = vb + (size_t)bid*(64*56);

  // ---- logits = Q K^T
  f32x4 a[4][4] = {};
#pragma unroll
  for (int kt = 0; kt < 2; ++kt) {
    f16x8 qf[4], kf[4];
#pragma unroll
    for (int mt = 0; mt < 4; ++mt) {
      int s = mt*16 + l15; if (s > 48) s = 48;   // clamp pad rows (masked later)
      qf[mt] = *(const f16x8*)(q + s*64 + kt*32 + quad*8);
      kf[mt] = *(const f16x8*)(k + s*64 + kt*32 + quad*8);
    }
#pragma unroll
    for (int mt = 0; mt < 4; ++mt)
#pragma unroll
      for (int nt = 0; nt < 4; ++nt)
        a[mt][nt] = __builtin_amdgcn_mfma_f32_16x16x32_f16(qf[mt], kf[nt], a[mt][nt], 0, 0, 0);
  }

  // ---- softmax rows (row = s_q = mt*16 + quad*4 + r ; col = s_k = nt*16 + l15)
  const float scale = 0.125f;
#pragma unroll
  for (int mt = 0; mt < 4; ++mt) {
    float mx[4] = {-1e30f,-1e30f,-1e30f,-1e30f};
#pragma unroll
    for (int nt = 0; nt < 4; ++nt) {
      int col = nt*16 + l15;
      bool valid = col < 49;
#pragma unroll
      for (int r = 0; r < 4; ++r) {
        float vv = valid ? a[mt][nt][r]*scale : -1e30f;
        a[mt][nt][r] = vv;
        mx[r] = fmaxf(mx[r], vv);
      }
    }
#pragma unroll
    for (int d = 1; d < 16; d <<= 1)
#pragma unroll
      for (int r = 0; r < 4; ++r) mx[r] = fmaxf(mx[r], __shfl_xor(mx[r], d, 64));
    float sm[4] = {0.f,0.f,0.f,0.f};
#pragma unroll
    for (int nt = 0; nt < 4; ++nt)
#pragma unroll
      for (int r = 0; r < 4; ++r) {
        float e = __expf(a[mt][nt][r] - mx[r]);
        a[mt][nt][r] = e;
        sm[r] += e;
      }
#pragma unroll
    for (int d = 1; d < 16; d <<= 1)
#pragma unroll
      for (int r = 0; r < 4; ++r) sm[r] += __shfl_xor(sm[r], d, 64);
#pragma unroll
    for (int nt = 0; nt < 4; ++nt)
#pragma unroll
      for (int r = 0; r < 4; ++r)
        P[(mt*16 + quad*4 + r)*72 + nt*16 + l15] = (f16)a[mt][nt][r];
    if (l15 == 0) {
#pragma unroll
      for (int r = 0; r < 4; ++r) lsum[mt*16 + quad*4 + r] = sm[r];
    }
  }
  __syncthreads();

  // ---- O^T[d][s_q] = sum_s V^T[d][s] * P[s_q][s]   (A=V^T rows, B=P rows)
  f32x4 o[4][4] = {};
#pragma unroll
  for (int kt = 0; kt < 2; ++kt) {
    int s0 = kt*32 + quad*8; if (s0 >= 56) s0 = 40;  // pad cols give P=0 anyway
    f16x8 vf[4], pf[4];
#pragma unroll
    for (int dt = 0; dt < 4; ++dt) vf[dt] = *(const f16x8*)(v + (dt*16 + l15)*56 + s0);
#pragma unroll
    for (int st = 0; st < 4; ++st) pf[st] = *(const f16x8*)&P[(st*16 + l15)*72 + kt*32 + quad*8];
#pragma unroll
    for (int dt = 0; dt < 4; ++dt)
#pragma unroll
      for (int st = 0; st < 4; ++st)
        o[dt][st] = __builtin_amdgcn_mfma_f32_16x16x32_f16(vf[dt], pf[st], o[dt][st], 0, 0, 0);
  }

  const int bg = bid >> 3, head = bid & 7;
#pragma unroll
  for (int st = 0; st < 4; ++st) {
    int sq = st*16 + l15;
    if (sq < 49) {
      float inv = 1.0f / lsum[sq];
#pragma unroll
      for (int dt = 0; dt < 4; ++dt) {
        int d0 = dt*16 + quad*4;
        f16x4 h4 = { (f16)(o[dt][st][0]*inv), (f16)(o[dt][st][1]*inv),
                     (f16)(o[dt][st][2]*inv), (f16)(o[dt][st][3]*inv) };
        *(f16x4*)(ob + (size_t)(bg*49 + sq)*512 + head*64 + d0) = h4;
      }
    }
  }
}

// ---------------------------------------------------------------------------
// k_proj: C[d][row_w] = sum_c Wp[d][c] * A[row_w][c]; +bias; scatter to token
// ---------------------------------------------------------------------------
__global__ __launch_bounds__(256) void k_proj(
    const f16* __restrict__ a16, const f16* __restrict__ w16,
    const float* __restrict__ bias, float* __restrict__ out)
{
  __shared__ __align__(16) f16 Wt[128*32];
  __shared__ __align__(16) f16 Xt[128*32];
  const int by = blockIdx.x;   // channel tile 0..3
  const int bx = blockIdx.y;   // windowed-row tile 0..783
  const int tid = threadIdx.x;
  const int wave = tid >> 6, ln = tid & 63;
  const int l15 = ln & 15, quad = ln >> 4;
  const int wq = wave >> 1, wp = wave & 1;

  f32x4 acc[4][4] = {};

  const int srow = wave*32 + (ln >> 2);
  const int scol = (ln & 3)*8;
  const f16* gW = w16 + (size_t)(by*128 + srow)*512 + scol;
  const f16* gX = a16 + (size_t)(bx*128 + srow)*512 + scol;
  f16* lW = &Wt[srow*32 + scol];
  f16* lX = &Xt[srow*32 + scol];

  for (int kt = 0; kt < 16; ++kt) {
    __syncthreads();
    gl_lds16(gW,          lW);
    gl_lds16(gW + 16*512, lW + 16*32);
    gl_lds16(gX,          lX);
    gl_lds16(gX + 16*512, lX + 16*32);
    gW += 32; gX += 32;
    __syncthreads();
    f16x8 af[4], bf[4];
#pragma unroll
    for (int i = 0; i < 4; ++i) af[i] = *(const f16x8*)&Wt[(wq*64 + i*16 + l15)*32 + quad*8];
#pragma unroll
    for (int j = 0; j < 4; ++j) bf[j] = *(const f16x8*)&Xt[(wp*64 + j*16 + l15)*32 + quad*8];
#pragma unroll
    for (int i = 0; i < 4; ++i)
#pragma unroll
      for (int j = 0; j < 4; ++j)
        acc[i][j] = __builtin_amdgcn_mfma_f32_16x16x32_f16(af[i], bf[j], acc[i][j], 0, 0, 0);
  }

#pragma unroll
  for (int j = 0; j < 4; ++j) {
    int m  = bx*128 + wp*64 + j*16 + l15;   // windowed row
    int b  = m / 3136;
    int rr = m - b*3136;
    int g  = rr / 49;
    int s  = rr - g*49;
    int gh = g >> 3, gw = g & 7;
    int p  = s / 7,  qx = s - p*7;
    int hh = gh*7 + p, ww = gw*7 + qx;
    size_t tok = (size_t)b*3136 + hh*56 + ww;
#pragma unroll
    for (int i = 0; i < 4; ++i) {
      int d0 = by*128 + wq*64 + i*16 + quad*4;
      float4 bb = *(const float4*)(bias + d0);
      float4 o4 = make_float4(acc[i][j][0]+bb.x, acc[i][j][1]+bb.y,
                              acc[i][j][2]+bb.z, acc[i][j][3]+bb.w);
      *(float4*)(out + tok*512 + d0) = o4;
    }
  }
}

// ---------------------------------------------------------------------------
extern "C" void kernel_launch(void* const* d_in, const int* in_sizes, int n_in,
                              void* d_out, int out_size, void* d_ws, size_t ws_size,
                              hipStream_t stream) {
  const float* x     = (const float*)d_in[0];
  const float* wqkv  = (const float*)d_in[1];
  const float* wproj = (const float*)d_in[2];
  const float* bias  = (const float*)d_in[3];

  char* ws = (char*)d_ws;
  // ws layout (bytes):
  //   [0, 102760448)            x16  -> later aliased by attn_out (fp16)
  //   [102760448, 104333312)    wqkv16
  //   [104333312, 104857600)    wproj16
  //   [104857600, +12544)       rope table (float2[49*32])
  //   [104873984, +117440512)   vT  [bgh][64][56] fp16
  f16*    x16   = (f16*)(ws);
  f16*    wq16  = (f16*)(ws + 102760448);
  f16*    wp16  = (f16*)(ws + 104333312);
  float2* tab   = (float2*)(ws + 104857600);
  f16*    vT    = (f16*)(ws + 104873984);
  f16*    attn16 = (f16*)(ws);              // aliases x16 (dead after k_qkv)

  // q,k live inside d_out (exactly 205,520,896 bytes); dead before k_proj writes
  f16* qbuf = (f16*)d_out;
  f16* kbuf = (f16*)((char*)d_out + 102760448);
  float* out = (float*)d_out;

  k_prep<<<dim3(25088 + 384 + 128 + 7), dim3(256), 0, stream>>>(
      x, wqkv, wproj, x16, wq16, wp16, tab);
  k_qkv<<<dim3(12, 784), dim3(256), 0, stream>>>(x16, wq16, tab, qbuf, kbuf, vT);
  k_attn<<<dim3(16384), dim3(64), 0, stream>>>(qbuf, kbuf, vT, attn16);
  k_proj<<<dim3(4, 784), dim3(256), 0, stream>>>(attn16, wp16, bias, out);
}

// Round 2
// 889.748 us; speedup vs baseline: 1.0760x; 1.0760x over previous
//
#include <hip/hip_runtime.h>
#include <stdint.h>
#include <stddef.h>

typedef _Float16 f16;
typedef _Float16 f16x8 __attribute__((ext_vector_type(8)));
typedef _Float16 f16x4 __attribute__((ext_vector_type(4)));
typedef float    f32x4 __attribute__((ext_vector_type(4)));

#define AS1 __attribute__((address_space(1)))
#define AS3 __attribute__((address_space(3)))

__device__ __forceinline__ void gl_lds16(const f16* g, f16* l) {
  // async global->LDS, 16B per lane; LDS dest is uniform base + lane*16
  __builtin_amdgcn_global_load_lds((const AS1 uint32_t*)g, (AS3 uint32_t*)l, 16, 0, 0);
}

// Problem constants: B=32, H=W=56, C=512, nh=8, hd=64, ws=7, S=49, G=64
// tokens/batch = 3136, M_total = 100352

// ---------------------------------------------------------------------------
// k_prep: fp32->fp16 conversions + RoPE table (49 x 32 float2 cos/sin)
// ---------------------------------------------------------------------------
__global__ __launch_bounds__(256) void k_prep(
    const float* __restrict__ x, const float* __restrict__ wqkv,
    const float* __restrict__ wproj,
    f16* __restrict__ x16, f16* __restrict__ wqkv16, f16* __restrict__ wproj16,
    float2* __restrict__ tab)
{
  const int XB = 25088, WQ = 384, WP = 128;  // blocks per region (8 elems/thread)
  int b = blockIdx.x, t = threadIdx.x;
  const float* src; f16* dst; long i0;
  if (b < XB)            { src = x;     dst = x16;     i0 = ((long)b*256 + t)*8; }
  else if (b < XB+WQ)    { src = wqkv;  dst = wqkv16;  i0 = ((long)(b-XB)*256 + t)*8; }
  else if (b < XB+WQ+WP) { src = wproj; dst = wproj16; i0 = ((long)(b-XB-WQ)*256 + t)*8; }
  else {
    int id = (b - XB - WQ - WP)*256 + t;
    if (id < 49*32) {
      int s = id >> 5, i = id & 31, j = i >> 1;
      float freq = expf(-(float)(4*j)*(1.0f/64.0f)*9.210340372f); // 10000^(-4j/64)
      float pos = (i & 1) ? (float)(s/7) : (float)(s%7);          // odd=y, even=x
      float a = pos * freq;
      tab[id] = make_float2(cosf(a), sinf(a));
    }
    return;
  }
  const float4* s4 = (const float4*)(src + i0);
  float4 v0 = s4[0], v1 = s4[1];
  f16x8 h = { (f16)v0.x,(f16)v0.y,(f16)v0.z,(f16)v0.w,
              (f16)v1.x,(f16)v1.y,(f16)v1.z,(f16)v1.w };
  *(f16x8*)(dst + i0) = h;
}

// ---------------------------------------------------------------------------
// GEMM core (shared by k_qkv / k_proj): BK=64, 128x128 tile, XOR-swizzled LDS.
// LDS rows are 64 f16 = 128 B = exactly one bank cycle; chunk c (16B) of row r
// is stored at physical position c ^ (r&7). Staging achieves this by permuting
// the per-lane GLOBAL source (LDS side of global_load_lds is fixed lane*16).
// ---------------------------------------------------------------------------
#define GEMM_STAGE(gW, gX, Wt, Xt, kt)                                        \
  {                                                                           \
    int srow = ln >> 3;                   /* 0..7 within one 1KB instr */     \
    int schunk = (ln & 7) ^ srow;         /* swizzled 16B chunk        */     \
    size_t goff = (size_t)srow * 512 + (kt)*64 + schunk * 8;                  \
    _Pragma("unroll")                                                         \
    for (int ii = 0; ii < 4; ++ii) {                                          \
      int r0 = wave * 32 + ii * 8;                                            \
      gl_lds16(gW + (size_t)r0 * 512 + goff, Wt + r0 * 64);                   \
      gl_lds16(gX + (size_t)r0 * 512 + goff, Xt + r0 * 64);                   \
    }                                                                         \
  }

#define GEMM_MAIN(Wt, Xt)                                                     \
  _Pragma("unroll")                                                           \
  for (int k2 = 0; k2 < 2; ++k2) {                                            \
    f16x8 af[4], bf[4];                                                       \
    int pc = ((k2 * 4 + quad) ^ (l15 & 7)) * 8;                               \
    _Pragma("unroll")                                                         \
    for (int i = 0; i < 4; ++i)                                               \
      af[i] = *(const f16x8*)&Wt[(wq * 64 + i * 16 + l15) * 64 + pc];         \
    _Pragma("unroll")                                                         \
    for (int j = 0; j < 4; ++j)                                               \
      bf[j] = *(const f16x8*)&Xt[(wp * 64 + j * 16 + l15) * 64 + pc];         \
    _Pragma("unroll")                                                         \
    for (int i = 0; i < 4; ++i)                                               \
      _Pragma("unroll")                                                       \
      for (int j = 0; j < 4; ++j)                                             \
        acc[i][j] = __builtin_amdgcn_mfma_f32_16x16x32_f16(af[i], bf[j],      \
                                                           acc[i][j], 0, 0, 0);\
  }

// ---------------------------------------------------------------------------
// k_qkv: C[ch][tok] = sum_k W[ch][k] * X[tok][k]
//   epilogue: RoPE on q/k; q,k,v all stored [bgh][s][64] (coalesced f16x4)
// ---------------------------------------------------------------------------
__global__ __launch_bounds__(256) void k_qkv(
    const f16* __restrict__ x16, const f16* __restrict__ w16,
    const float2* __restrict__ tab,
    f16* __restrict__ qb, f16* __restrict__ kb, f16* __restrict__ vb)
{
  __shared__ __align__(16) f16 Wt[128*64];
  __shared__ __align__(16) f16 Xt[128*64];
  const int by = blockIdx.x;   // channel tile 0..11  (0-3 q, 4-7 k, 8-11 v)
  const int bx = blockIdx.y;   // token tile 0..783
  const int tid = threadIdx.x;
  const int wave = tid >> 6, ln = tid & 63;
  const int l15 = ln & 15, quad = ln >> 4;
  const int wq = wave >> 1, wp = wave & 1;

  f32x4 acc[4][4] = {};
  const f16* gW = w16 + (size_t)(by*128)*512;
  const f16* gX = x16 + (size_t)(bx*128)*512;

  for (int kt = 0; kt < 8; ++kt) {
    __syncthreads();
    GEMM_STAGE(gW, gX, Wt, Xt, kt);
    __syncthreads();
    GEMM_MAIN(Wt, Xt);
  }

  const int t = (by*128) >> 9;   // 0=q,1=k,2=v (uniform per block)
#pragma unroll
  for (int j = 0; j < 4; ++j) {
    int m  = bx*128 + wp*64 + j*16 + l15;   // token (token-order)
    int b  = m / 3136;
    int nn = m - b*3136;
    int hh = nn / 56, ww = nn - hh*56;
    int gh = hh / 7,  p  = hh - gh*7;
    int gw = ww / 7,  qx = ww - gw*7;
    int g  = gh*8 + gw;
    int s  = p*7 + qx;
    int bg = b*64 + g;
#pragma unroll
    for (int i = 0; i < 4; ++i) {
      int c0   = by*128 + wq*64 + i*16 + quad*4;  // global channel of reg 0
      int cin  = c0 & 511;
      int head = cin >> 6;
      int dd   = cin & 63;                        // multiple of 4
      float v0 = acc[i][j][0], v1 = acc[i][j][1], v2 = acc[i][j][2], v3 = acc[i][j][3];
      f16x4 h4;
      if (t < 2) {
        float2 t0 = tab[s*32 + (dd >> 1)];
        float2 t1 = tab[s*32 + (dd >> 1) + 1];
        h4[0] = (f16)(v0*t0.x - v1*t0.y);
        h4[1] = (f16)(v0*t0.y + v1*t0.x);
        h4[2] = (f16)(v2*t1.x - v3*t1.y);
        h4[3] = (f16)(v2*t1.y + v3*t1.x);
      } else {
        h4[0] = (f16)v0; h4[1] = (f16)v1; h4[2] = (f16)v2; h4[3] = (f16)v3;
      }
      f16* dst = (t == 0 ? qb : (t == 1 ? kb : vb))
               + (size_t)((bg*8 + head)*49 + s)*64 + dd;
      *(f16x4*)dst = h4;
    }
  }
}

// ---------------------------------------------------------------------------
// k_attn: one wave per (b,g,head).  S=49 padded to 64 via clamp+mask.
//   V staged into LDS (coalesced), V^T fragments built with ds_read_u16.
// ---------------------------------------------------------------------------
__global__ __launch_bounds__(64) void k_attn(
    const f16* __restrict__ qb, const f16* __restrict__ kb,
    const f16* __restrict__ vb, f16* __restrict__ ob)
{
  __shared__ __align__(16) f16 Vt[64*64];  // V rows (rows 49..63 = garbage, masked by P=0)
  __shared__ __align__(16) f16 P[64*72];   // unnormalized exp, stride 72 (144B)
  __shared__ float lsum[64];
  const int bid = blockIdx.x;
  const int ln = threadIdx.x, l15 = ln & 15, quad = ln >> 4;
  const f16* q = qb + (size_t)bid*(49*64);
  const f16* k = kb + (size_t)bid*(49*64);
  const f16* v = vb + (size_t)bid*(49*64);

  // stage V: 64 rows x 128 B (reads 15 rows past this window; vb is padded)
#pragma unroll
  for (int i = 0; i < 8; ++i)
    gl_lds16(v + (size_t)(i*8 + (ln>>3))*64 + (ln&7)*8, Vt + i*512);

  // ---- logits = Q K^T
  f32x4 a[4][4] = {};
#pragma unroll
  for (int kt = 0; kt < 2; ++kt) {
    f16x8 qf[4], kf[4];
#pragma unroll
    for (int mt = 0; mt < 4; ++mt) {
      int s = mt*16 + l15; if (s > 48) s = 48;   // clamp pad rows (masked later)
      qf[mt] = *(const f16x8*)(q + s*64 + kt*32 + quad*8);
      kf[mt] = *(const f16x8*)(k + s*64 + kt*32 + quad*8);
    }
#pragma unroll
    for (int mt = 0; mt < 4; ++mt)
#pragma unroll
      for (int nt = 0; nt < 4; ++nt)
        a[mt][nt] = __builtin_amdgcn_mfma_f32_16x16x32_f16(qf[mt], kf[nt], a[mt][nt], 0, 0, 0);
  }

  // ---- softmax rows (row = s_q = mt*16 + quad*4 + r ; col = s_k = nt*16 + l15)
  const float scale = 0.125f;
#pragma unroll
  for (int mt = 0; mt < 4; ++mt) {
    float mx[4] = {-1e30f,-1e30f,-1e30f,-1e30f};
#pragma unroll
    for (int nt = 0; nt < 4; ++nt) {
      int col = nt*16 + l15;
      bool valid = col < 49;
#pragma unroll
      for (int r = 0; r < 4; ++r) {
        float vv = valid ? a[mt][nt][r]*scale : -1e30f;
        a[mt][nt][r] = vv;
        mx[r] = fmaxf(mx[r], vv);
      }
    }
#pragma unroll
    for (int d = 1; d < 16; d <<= 1)
#pragma unroll
      for (int r = 0; r < 4; ++r) mx[r] = fmaxf(mx[r], __shfl_xor(mx[r], d, 64));
    float sm[4] = {0.f,0.f,0.f,0.f};
#pragma unroll
    for (int nt = 0; nt < 4; ++nt)
#pragma unroll
      for (int r = 0; r < 4; ++r) {
        float e = __expf(a[mt][nt][r] - mx[r]);
        a[mt][nt][r] = e;
        sm[r] += e;
      }
#pragma unroll
    for (int d = 1; d < 16; d <<= 1)
#pragma unroll
      for (int r = 0; r < 4; ++r) sm[r] += __shfl_xor(sm[r], d, 64);
#pragma unroll
    for (int nt = 0; nt < 4; ++nt)
#pragma unroll
      for (int r = 0; r < 4; ++r)
        P[(mt*16 + quad*4 + r)*72 + nt*16 + l15] = (f16)a[mt][nt][r];
    if (l15 == 0) {
#pragma unroll
      for (int r = 0; r < 4; ++r) lsum[mt*16 + quad*4 + r] = sm[r];
    }
  }
  __syncthreads();   // also drains the global_load_lds staging of Vt

  // ---- O^T[d][s_q] = sum_s V^T[d][s] * P[s_q][s]   (A=V^T rows, B=P rows)
  f32x4 o[4][4] = {};
#pragma unroll
  for (int kt = 0; kt < 2; ++kt) {
    const int s0 = kt*32 + quad*8;
    f16x8 vf[4], pf[4];
#pragma unroll
    for (int dt = 0; dt < 4; ++dt)
#pragma unroll
      for (int j = 0; j < 8; ++j)
        vf[dt][j] = Vt[(s0 + j)*64 + dt*16 + l15];
#pragma unroll
    for (int st = 0; st < 4; ++st) pf[st] = *(const f16x8*)&P[(st*16 + l15)*72 + s0];
#pragma unroll
    for (int dt = 0; dt < 4; ++dt)
#pragma unroll
      for (int st = 0; st < 4; ++st)
        o[dt][st] = __builtin_amdgcn_mfma_f32_16x16x32_f16(vf[dt], pf[st], o[dt][st], 0, 0, 0);
  }

  const int bg = bid >> 3, head = bid & 7;
#pragma unroll
  for (int st = 0; st < 4; ++st) {
    int sq = st*16 + l15;
    if (sq < 49) {
      float inv = 1.0f / lsum[sq];
#pragma unroll
      for (int dt = 0; dt < 4; ++dt) {
        int d0 = dt*16 + quad*4;
        f16x4 h4 = { (f16)(o[dt][st][0]*inv), (f16)(o[dt][st][1]*inv),
                     (f16)(o[dt][st][2]*inv), (f16)(o[dt][st][3]*inv) };
        *(f16x4*)(ob + (size_t)(bg*49 + sq)*512 + head*64 + d0) = h4;
      }
    }
  }
}

// ---------------------------------------------------------------------------
// k_proj: C[d][row_w] = sum_c Wp[d][c] * A[row_w][c]; +bias; scatter to token
// ---------------------------------------------------------------------------
__global__ __launch_bounds__(256) void k_proj(
    const f16* __restrict__ a16, const f16* __restrict__ w16,
    const float* __restrict__ bias, float* __restrict__ out)
{
  __shared__ __align__(16) f16 Wt[128*64];
  __shared__ __align__(16) f16 Xt[128*64];
  const int by = blockIdx.x;   // channel tile 0..3
  const int bx = blockIdx.y;   // windowed-row tile 0..783
  const int tid = threadIdx.x;
  const int wave = tid >> 6, ln = tid & 63;
  const int l15 = ln & 15, quad = ln >> 4;
  const int wq = wave >> 1, wp = wave & 1;

  f32x4 acc[4][4] = {};
  const f16* gW = w16 + (size_t)(by*128)*512;
  const f16* gX = a16 + (size_t)(bx*128)*512;

  for (int kt = 0; kt < 8; ++kt) {
    __syncthreads();
    GEMM_STAGE(gW, gX, Wt, Xt, kt);
    __syncthreads();
    GEMM_MAIN(Wt, Xt);
  }

#pragma unroll
  for (int j = 0; j < 4; ++j) {
    int m  = bx*128 + wp*64 + j*16 + l15;   // windowed row
    int b  = m / 3136;
    int rr = m - b*3136;
    int g  = rr / 49;
    int s  = rr - g*49;
    int gh = g >> 3, gw = g & 7;
    int p  = s / 7,  qx = s - p*7;
    int hh = gh*7 + p, ww = gw*7 + qx;
    size_t tok = (size_t)b*3136 + hh*56 + ww;
#pragma unroll
    for (int i = 0; i < 4; ++i) {
      int d0 = by*128 + wq*64 + i*16 + quad*4;
      float4 bb = *(const float4*)(bias + d0);
      float4 o4 = make_float4(acc[i][j][0]+bb.x, acc[i][j][1]+bb.y,
                              acc[i][j][2]+bb.z, acc[i][j][3]+bb.w);
      *(float4*)(out + tok*512 + d0) = o4;
    }
  }
}

// ---------------------------------------------------------------------------
extern "C" void kernel_launch(void* const* d_in, const int* in_sizes, int n_in,
                              void* d_out, int out_size, void* d_ws, size_t ws_size,
                              hipStream_t stream) {
  const float* x     = (const float*)d_in[0];
  const float* wqkv  = (const float*)d_in[1];
  const float* wproj = (const float*)d_in[2];
  const float* bias  = (const float*)d_in[3];

  char* ws = (char*)d_ws;
  // ws layout (bytes):
  //   [0, 102760448)            x16  -> later aliased by attn_out (fp16)
  //   [102760448, 104333312)    wqkv16
  //   [104333312, 104857600)    wproj16
  //   [104857600, +12544)       rope table (float2[49*32])
  //   [104873984, +102768640)   v [bgh][49][64] fp16 (+8KB pad for Vt staging overrun)
  f16*    x16   = (f16*)(ws);
  f16*    wq16  = (f16*)(ws + 102760448);
  f16*    wp16  = (f16*)(ws + 104333312);
  float2* tab   = (float2*)(ws + 104857600);
  f16*    vbuf  = (f16*)(ws + 104873984);
  f16*    attn16 = (f16*)(ws);              // aliases x16 (dead after k_qkv)

  // q,k live inside d_out (205,520,896 bytes); dead before k_proj writes
  f16* qbuf = (f16*)d_out;
  f16* kbuf = (f16*)((char*)d_out + 102760448);
  float* out = (float*)d_out;

  k_prep<<<dim3(25088 + 384 + 128 + 7), dim3(256), 0, stream>>>(
      x, wqkv, wproj, x16, wq16, wp16, tab);
  k_qkv<<<dim3(12, 784), dim3(256), 0, stream>>>(x16, wq16, tab, qbuf, kbuf, vbuf);
  k_attn<<<dim3(16384), dim3(64), 0, stream>>>(qbuf, kbuf, vbuf, attn16);
  k_proj<<<dim3(4, 784), dim3(256), 0, stream>>>(attn16, wp16, bias, out);
}